// Round 2
// baseline (424.603 us; speedup 1.0000x reference)
//
#include <hip/hip_runtime.h>
#include <math.h>

// Problem constants (fixed by reference setup_inputs)
#define T_TOK 16384   // B*S
#define DDIM  2048
#define NE    64      // experts
#define NWAVE 8       // waves per block = K-split factor
#define KRANGE 256    // k-span per wave
#define KCH   16      // k per chunk
#define NCHUNK (KRANGE / KCH)
#define XPAD  66      // padded token-stride for transposed x staging

// Output layout in d_out (float):
//   [0 .. 32767]      expert_indices as float, token-major, k-minor
//   [32768 .. 65535]  expert_weights
//   [65536]           aux_loss

__global__ __launch_bounds__(512, 2)
void router_main(const float* __restrict__ x, const float* __restrict__ W,
                 float* __restrict__ out, double* __restrict__ usage) {
    // 128 KB LDS, time-multiplexed:
    //   phase 1 (GEMM): first 8*KCH*XPAD floats = per-wave transposed x staging
    //   phase 2 (reduce): P[w][e][t] xor-swizzled partial logits (32768 floats)
    __shared__ float smem[32768];

    const int tid  = threadIdx.x;
    const int lane = tid & 63;                                  // token-in-block
    const int w    = __builtin_amdgcn_readfirstlane(tid >> 6);  // wave id (uniform!)
    const int t0   = blockIdx.x * 64;
    const int kbase = w * KRANGE;

    float* xs = smem + w * (KCH * XPAD);   // wave-private staging

    float acc[NE];
#pragma unroll
    for (int e = 0; e < NE; ++e) acc[e] = 0.f;

    const int r  = lane >> 2;   // 0..15: token row within a load group
    const int kq = lane & 3;    // float4 slot within 16-k chunk

    // prefetch chunk 0 (coalesced: 16 rows x 64B per instruction)
    float4 pf[4];
#pragma unroll
    for (int i = 0; i < 4; ++i)
        pf[i] = *(const float4*)&x[(size_t)(t0 + i * 16 + r) * DDIM + kbase + kq * 4];

#pragma unroll 1
    for (int c = 0; c < NCHUNK; ++c) {
        // transpose current chunk into LDS: xs[k][t], stride 66 (conflict-free)
#pragma unroll
        for (int i = 0; i < 4; ++i) {
            const int t = i * 16 + r;
            xs[(kq * 4 + 0) * XPAD + t] = pf[i].x;
            xs[(kq * 4 + 1) * XPAD + t] = pf[i].y;
            xs[(kq * 4 + 2) * XPAD + t] = pf[i].z;
            xs[(kq * 4 + 3) * XPAD + t] = pf[i].w;
        }
        // prefetch next chunk (independent of LDS ops above)
        if (c + 1 < NCHUNK) {
#pragma unroll
            for (int i = 0; i < 4; ++i)
                pf[i] = *(const float4*)&x[(size_t)(t0 + i * 16 + r) * DDIM +
                                           kbase + (c + 1) * KCH + kq * 4];
        }
        // my token's 16 k-values -> VGPRs (1 ds_read_b32 feeds 64 FMAs)
        float xv[KCH];
#pragma unroll
        for (int k = 0; k < KCH; ++k) xv[k] = xs[k * XPAD + lane];

        // expert loop: W addresses are wave-uniform -> s_load (scalar pipe)
        const float* Wp = W + kbase + c * KCH;
#pragma unroll
        for (int e = 0; e < NE; ++e) {
            const float* wr = Wp + (size_t)e * DDIM;
#pragma unroll
            for (int k = 0; k < KCH; ++k)
                acc[e] = fmaf(xv[k], wr[k], acc[e]);
        }
    }

    // ---- cross-wave K reduction via LDS (xor-swizzle: conflict-free both ways)
    __syncthreads();
#pragma unroll
    for (int e = 0; e < NE; ++e)
        smem[((w * 64 + e) << 6) + (lane ^ e)] = acc[e];
    __syncthreads();

    // ---- epilogue: lane = expert, 8 tokens per wave
    float usage_acc = 0.f;
    for (int j = 0; j < 8; ++j) {
        const int tl = w * 8 + j;      // local token 0..63
        const int t  = t0 + tl;        // global token

        float l = 0.f;
#pragma unroll
        for (int ww = 0; ww < NWAVE; ++ww)
            l += smem[((ww * 64 + lane) << 6) + (tl ^ lane)];

        // top-1 (tie -> lower index, matching jax.lax.top_k)
        float v1 = l; int i1 = lane;
#pragma unroll
        for (int off = 32; off >= 1; off >>= 1) {
            float ov = __shfl_xor(v1, off, 64);
            int   oi = __shfl_xor(i1, off, 64);
            if (ov > v1 || (ov == v1 && oi < i1)) { v1 = ov; i1 = oi; }
        }
        // top-2
        float lm = (lane == i1) ? -INFINITY : l;
        float v2 = lm; int i2 = lane;
#pragma unroll
        for (int off = 32; off >= 1; off >>= 1) {
            float ov = __shfl_xor(v2, off, 64);
            int   oi = __shfl_xor(i2, off, 64);
            if (ov > v2 || (ov == v2 && oi < i2)) { v2 = ov; i2 = oi; }
        }

        // full softmax denom (for usage) + top-2 weights
        float p = expf(l - v1);
        float s = p;
#pragma unroll
        for (int off = 32; off >= 1; off >>= 1) s += __shfl_xor(s, off, 64);

        float e2  = expf(v2 - v1);
        float rcp = 1.0f / (1.0f + e2);

        usage_acc += p / s;

        if (lane == 0) {
            out[(size_t)t * 2 + 0]         = (float)i1;
            out[(size_t)t * 2 + 1]         = (float)i2;
            out[32768 + (size_t)t * 2 + 0] = rcp;
            out[32768 + (size_t)t * 2 + 1] = e2 * rcp;
        }
    }

    // ---- usage: block-reduce in LDS, ONE fp64 atomic per block per expert
    __syncthreads();
    smem[(w << 6) + lane] = usage_acc;
    __syncthreads();
    if (w == 0) {
        float s = 0.f;
#pragma unroll
        for (int ww = 0; ww < NWAVE; ++ww) s += smem[(ww << 6) + lane];
        atomicAdd(&usage[lane], (double)s);
    }
}

__global__ void router_aux(const double* __restrict__ usage, float* __restrict__ out) {
    int lane = threadIdx.x;  // 64 threads
    double u  = usage[lane] * (1.0 / 16384.0) - (1.0 / 64.0);
    double sq = u * u;
#pragma unroll
    for (int off = 32; off >= 1; off >>= 1) sq += __shfl_xor(sq, off, 64);
    if (lane == 0) out[65536] = (float)sq;
}

extern "C" void kernel_launch(void* const* d_in, const int* in_sizes, int n_in,
                              void* d_out, int out_size, void* d_ws, size_t ws_size,
                              hipStream_t stream) {
    const float* x = (const float*)d_in[0];   // [4,4096,2048] fp32
    const float* W = (const float*)d_in[1];   // [64,2048] fp32
    float* out     = (float*)d_out;           // 65537 floats
    double* usage  = (double*)d_ws;           // 64 doubles of scratch

    hipMemsetAsync(usage, 0, NE * sizeof(double), stream);
    router_main<<<dim3(T_TOK / 64), dim3(512), 0, stream>>>(x, W, out, usage);
    router_aux<<<dim3(1), dim3(64), 0, stream>>>(usage, out);
}

// Round 3
// 312.074 us; speedup vs baseline: 1.3606x; 1.3606x over previous
//
#include <hip/hip_runtime.h>
#include <math.h>

// Problem constants (fixed by reference setup_inputs)
#define T_TOK  16384
#define DDIM   2048
#define NE     64
#define EPW    8        // experts per wave (E-split 8)
#define KQ     1024     // k per k-half     (K-split 2)
#define KC     64       // k per staged chunk per half
#define NITER  (KQ / KC)   // 16
#define XPAD   65       // odd pad -> bank (k + t) % 32, 2-way = free
#define XSQ    (KC * XPAD) // 4160 floats per half
#define SMEMF  (2 * XSQ)   // 8320 floats = 33.3 KB (also holds P=8192 & usage=1024)

// Output layout in d_out (float):
//   [0 .. 32767]      expert_indices as float, token-major, k-minor
//   [32768 .. 65535]  expert_weights
//   [65536]           aux_loss

__global__ __launch_bounds__(1024, 4)
void router_main(const float* __restrict__ x, const float* __restrict__ W,
                 float* __restrict__ out, float* __restrict__ usage_part) {
    __shared__ float smem[SMEMF];

    const int tid  = threadIdx.x;
    const int lane = tid & 63;                                   // token-in-block
    const int w    = __builtin_amdgcn_readfirstlane(tid >> 6);   // wave 0..15 (uniform)
    const int we   = w >> 1;    // expert group 0..7 -> experts [8we, 8we+8)
    const int wq   = w & 1;     // k half
    const int t0   = blockIdx.x * 64;

    const float* Wb = W + (size_t)(we * EPW) * DDIM + wq * KQ;   // uniform base

    float acc[EPW];
#pragma unroll
    for (int e = 0; e < EPW; ++e) acc[e] = 0.f;

    // staging role: thread -> (token st, float4-col skq), one float4 per k-half
    const int st  = tid >> 4;    // 0..63
    const int skq = tid & 15;    // 0..15
    const float* xrow = x + (size_t)(t0 + st) * DDIM + skq * 4;

    float4 pf[2];
#pragma unroll
    for (int q = 0; q < 2; ++q) pf[q] = *(const float4*)&xrow[q * KQ];

#pragma unroll 1
    for (int c = 0; c < NITER; ++c) {
        // transpose-write staged chunk: xs[half][k][t], stride 65
#pragma unroll
        for (int q = 0; q < 2; ++q) {
            float* dst = &smem[q * XSQ + (skq * 4) * XPAD + st];
            dst[0 * XPAD] = pf[q].x;
            dst[1 * XPAD] = pf[q].y;
            dst[2 * XPAD] = pf[q].z;
            dst[3 * XPAD] = pf[q].w;
        }
        // prefetch next chunk while this one is consumed
        if (c + 1 < NITER) {
#pragma unroll
            for (int q = 0; q < 2; ++q)
                pf[q] = *(const float4*)&xrow[q * KQ + (c + 1) * KC];
        }
        __syncthreads();

        const float* Wc = Wb + c * KC;          // uniform -> s_load
        const float* xq = &smem[wq * XSQ];
#pragma unroll 1
        for (int k4 = 0; k4 < KC / 4; ++k4) {
            float xv0 = xq[(k4 * 4 + 0) * XPAD + lane];
            float xv1 = xq[(k4 * 4 + 1) * XPAD + lane];
            float xv2 = xq[(k4 * 4 + 2) * XPAD + lane];
            float xv3 = xq[(k4 * 4 + 3) * XPAD + lane];
#pragma unroll
            for (int e = 0; e < EPW; ++e) {
                const float* wr = Wc + (size_t)e * DDIM + k4 * 4;  // uniform
                acc[e] = fmaf(xv0, wr[0], acc[e]);
                acc[e] = fmaf(xv1, wr[1], acc[e]);
                acc[e] = fmaf(xv2, wr[2], acc[e]);
                acc[e] = fmaf(xv3, wr[3], acc[e]);
            }
        }
        __syncthreads();
    }

    // partial logits -> LDS: P[e][wq][t^e] at e*128 + wq*64 + (t^e)  (2-way, free)
#pragma unroll
    for (int j = 0; j < EPW; ++j) {
        const int e = we * EPW + j;
        smem[e * 128 + wq * 64 + (lane ^ e)] = acc[j];
    }
    __syncthreads();

    // ---- epilogue: lane = expert, 4 tokens per wave (verified logic, rounds 1-2)
    float usage_acc = 0.f;
#pragma unroll 1
    for (int j = 0; j < 4; ++j) {
        const int tl = w * 4 + j;
        const int t  = t0 + tl;
        float l = smem[lane * 128 + (tl ^ lane)] +
                  smem[lane * 128 + 64 + (tl ^ lane)];

        float v1 = l; int i1 = lane;
#pragma unroll
        for (int off = 32; off >= 1; off >>= 1) {
            float ov = __shfl_xor(v1, off, 64);
            int   oi = __shfl_xor(i1, off, 64);
            if (ov > v1 || (ov == v1 && oi < i1)) { v1 = ov; i1 = oi; }
        }
        float lm = (lane == i1) ? -INFINITY : l;
        float v2 = lm; int i2 = lane;
#pragma unroll
        for (int off = 32; off >= 1; off >>= 1) {
            float ov = __shfl_xor(v2, off, 64);
            int   oi = __shfl_xor(i2, off, 64);
            if (ov > v2 || (ov == v2 && oi < i2)) { v2 = ov; i2 = oi; }
        }

        float p = expf(l - v1);
        float s = p;
#pragma unroll
        for (int off = 32; off >= 1; off >>= 1) s += __shfl_xor(s, off, 64);

        float e2  = expf(v2 - v1);
        float rcp = 1.0f / (1.0f + e2);
        usage_acc += p / s;

        if (lane == 0) {
            out[(size_t)t * 2 + 0]         = (float)i1;
            out[(size_t)t * 2 + 1]         = (float)i2;
            out[32768 + (size_t)t * 2 + 0] = rcp;
            out[32768 + (size_t)t * 2 + 1] = e2 * rcp;
        }
    }

    // ---- per-block usage partials (no atomics; deterministic)
    __syncthreads();
    smem[w * 64 + lane] = usage_acc;
    __syncthreads();
    if (w == 0) {
        float s = 0.f;
#pragma unroll
        for (int ww = 0; ww < 16; ++ww) s += smem[ww * 64 + lane];
        usage_part[(size_t)blockIdx.x * 64 + lane] = s;
    }
}

__global__ void router_aux(const float* __restrict__ usage_part, float* __restrict__ out) {
    __shared__ float red[4][NE];
    const int tid  = threadIdx.x;   // 256
    const int e    = tid & 63;
    const int part = tid >> 6;      // 0..3
    float s = 0.f;
    for (int b = part; b < 256; b += 4) s += usage_part[(size_t)b * 64 + e];
    red[part][e] = s;
    __syncthreads();
    if (part == 0) {
        float u = ((red[0][e] + red[1][e]) + (red[2][e] + red[3][e]))
                  * (1.0f / 16384.0f) - (1.0f / 64.0f);
        float sq = u * u;
#pragma unroll
        for (int off = 32; off >= 1; off >>= 1) sq += __shfl_xor(sq, off, 64);
        if (e == 0) out[65536] = sq;
    }
}

extern "C" void kernel_launch(void* const* d_in, const int* in_sizes, int n_in,
                              void* d_out, int out_size, void* d_ws, size_t ws_size,
                              hipStream_t stream) {
    const float* x = (const float*)d_in[0];   // [4,4096,2048] fp32
    const float* W = (const float*)d_in[1];   // [64,2048] fp32
    float* out     = (float*)d_out;           // 65537 floats
    float* upart   = (float*)d_ws;            // 256*64 floats of scratch

    router_main<<<dim3(T_TOK / 64), dim3(1024), 0, stream>>>(x, W, out, upart);
    router_aux<<<dim3(1), dim3(256), 0, stream>>>(upart, out);
}

// Round 4
// 281.902 us; speedup vs baseline: 1.5062x; 1.1070x over previous
//
#include <hip/hip_runtime.h>
#include <math.h>

// Problem constants (fixed by reference setup_inputs)
#define T_TOK 16384
#define DDIM  2048
#define NE    64
#define NPLANE (NE * DDIM)      // 131072 elements per W split plane
#define NBLK  512               // main-kernel grid (32 tokens each)

typedef __attribute__((ext_vector_type(8))) short short8;   // 8 bf16 MFMA frag
typedef __attribute__((ext_vector_type(4))) float floatx4;  // MFMA C/D

union Frag8 { unsigned short u[8]; short8 v; uint4 q; };

__device__ __forceinline__ unsigned int bf16_rne_bits(float x) {
    unsigned int u = __builtin_bit_cast(unsigned int, x);
    return (u + 0x7fffu + ((u >> 16) & 1u)) & 0xffff0000u;
}

// ---- pre-kernel: exact 3-way bf16 split of W (fp32 = h + m + l, exact) ----
__global__ void wsplit_kernel(const float* __restrict__ W,
                              unsigned short* __restrict__ wh,
                              unsigned short* __restrict__ wm,
                              unsigned short* __restrict__ wl) {
    int i = blockIdx.x * 256 + threadIdx.x;   // grid covers exactly NPLANE
    float w = W[i];
    unsigned int hb = bf16_rne_bits(w);
    float r  = w - __builtin_bit_cast(float, hb);   // exact (Sterbenz)
    unsigned int mb = bf16_rne_bits(r);
    float r2 = r - __builtin_bit_cast(float, mb);   // exact
    unsigned int lb = bf16_rne_bits(r2);            // |err| <= 2^-24 |w|
    wh[i] = (unsigned short)(hb >> 16);
    wm[i] = (unsigned short)(mb >> 16);
    wl[i] = (unsigned short)(lb >> 16);
}

// ---- main: split-bf16 MFMA GEMM (6 passes = fp32-exact products) + top-2 ----
__global__ __launch_bounds__(256, 2)
void router_main(const float* __restrict__ x,
                 const unsigned short* __restrict__ wh,
                 const unsigned short* __restrict__ wm,
                 const unsigned short* __restrict__ wl,
                 float* __restrict__ out, float* __restrict__ usage_part) {
    __shared__ float lg[2][32][NE];    // per-k-half partial logits (16 KB)
    __shared__ float ured[4][NE];

    const int tid  = threadIdx.x;
    const int lane = tid & 63;
    const int wv   = __builtin_amdgcn_readfirstlane(tid >> 6);  // 0..3
    const int nh   = wv & 1;     // expert half  (32 experts)
    const int kh   = wv >> 1;    // k half       (1024 k)
    const int c    = lane & 15;  // frag row index (token / expert)
    const int q    = lane >> 4;  // frag k-quad
    const int t0   = blockIdx.x * 32;

    // A: token rows (fp32, coalesced 16-rows x 128B per step)
    const float* xr0 = x + (size_t)(t0 + c) * DDIM + kh * 1024 + q * 8;
    const float* xr1 = xr0 + (size_t)16 * DDIM;
    // B: expert rows in pre-split planes (L2-resident)
    const size_t bo0 = (size_t)(nh * 32 + c) * DDIM + kh * 1024 + q * 8;
    const size_t bo1 = bo0 + (size_t)16 * DDIM;

    floatx4 acc[2][2];
#pragma unroll
    for (int mt = 0; mt < 2; ++mt)
#pragma unroll
        for (int nt = 0; nt < 2; ++nt)
            acc[mt][nt] = (floatx4){0.f, 0.f, 0.f, 0.f};

    // register prefetch buffers (depth 1)
    float4 pa[2][2];     // [m-tile][lo/hi float4]  raw fp32 x
    uint4  pb[2][3];     // [n-tile][h/m/l]         bf16 B frags
    pa[0][0] = *(const float4*)(xr0 + 0);
    pa[0][1] = *(const float4*)(xr0 + 4);
    pa[1][0] = *(const float4*)(xr1 + 0);
    pa[1][1] = *(const float4*)(xr1 + 4);
    pb[0][0] = *(const uint4*)(wh + bo0);
    pb[0][1] = *(const uint4*)(wm + bo0);
    pb[0][2] = *(const uint4*)(wl + bo0);
    pb[1][0] = *(const uint4*)(wh + bo1);
    pb[1][1] = *(const uint4*)(wm + bo1);
    pb[1][2] = *(const uint4*)(wl + bo1);

#pragma unroll 1
    for (int s = 0; s < 32; ++s) {
        float4 ca[2][2];
        uint4  cb[2][3];
#pragma unroll
        for (int mt = 0; mt < 2; ++mt) { ca[mt][0] = pa[mt][0]; ca[mt][1] = pa[mt][1]; }
#pragma unroll
        for (int nt = 0; nt < 2; ++nt) { cb[nt][0] = pb[nt][0]; cb[nt][1] = pb[nt][1]; cb[nt][2] = pb[nt][2]; }

        if (s + 1 < 32) {
            const int sk = (s + 1) * 32;
            pa[0][0] = *(const float4*)(xr0 + sk);
            pa[0][1] = *(const float4*)(xr0 + sk + 4);
            pa[1][0] = *(const float4*)(xr1 + sk);
            pa[1][1] = *(const float4*)(xr1 + sk + 4);
            pb[0][0] = *(const uint4*)(wh + bo0 + sk);
            pb[0][1] = *(const uint4*)(wm + bo0 + sk);
            pb[0][2] = *(const uint4*)(wl + bo0 + sk);
            pb[1][0] = *(const uint4*)(wh + bo1 + sk);
            pb[1][1] = *(const uint4*)(wm + bo1 + sk);
            pb[1][2] = *(const uint4*)(wl + bo1 + sk);
        }

        // exact in-register split of A into h/m/l bf16 frags
        short8 Ah[2], Am[2], Al[2];
#pragma unroll
        for (int mt = 0; mt < 2; ++mt) {
            Frag8 fh, fm, fl;
            float f[8] = {ca[mt][0].x, ca[mt][0].y, ca[mt][0].z, ca[mt][0].w,
                          ca[mt][1].x, ca[mt][1].y, ca[mt][1].z, ca[mt][1].w};
#pragma unroll
            for (int j = 0; j < 8; ++j) {
                unsigned int hb = bf16_rne_bits(f[j]);
                float r  = f[j] - __builtin_bit_cast(float, hb);
                unsigned int mb = bf16_rne_bits(r);
                float r2 = r - __builtin_bit_cast(float, mb);
                unsigned int lb = bf16_rne_bits(r2);
                fh.u[j] = (unsigned short)(hb >> 16);
                fm.u[j] = (unsigned short)(mb >> 16);
                fl.u[j] = (unsigned short)(lb >> 16);
            }
            Ah[mt] = fh.v; Am[mt] = fm.v; Al[mt] = fl.v;
        }

        // 6 passes: hh + hm + mh + mm + hl + lh  (error <= 2^-24-class)
#pragma unroll
        for (int mt = 0; mt < 2; ++mt)
#pragma unroll
            for (int nt = 0; nt < 2; ++nt) {
                short8 Bh = __builtin_bit_cast(short8, cb[nt][0]);
                short8 Bm = __builtin_bit_cast(short8, cb[nt][1]);
                short8 Bl = __builtin_bit_cast(short8, cb[nt][2]);
                floatx4 a = acc[mt][nt];
                a = __builtin_amdgcn_mfma_f32_16x16x32_bf16(Ah[mt], Bh, a, 0, 0, 0);
                a = __builtin_amdgcn_mfma_f32_16x16x32_bf16(Ah[mt], Bm, a, 0, 0, 0);
                a = __builtin_amdgcn_mfma_f32_16x16x32_bf16(Am[mt], Bh, a, 0, 0, 0);
                a = __builtin_amdgcn_mfma_f32_16x16x32_bf16(Am[mt], Bm, a, 0, 0, 0);
                a = __builtin_amdgcn_mfma_f32_16x16x32_bf16(Ah[mt], Bl, a, 0, 0, 0);
                a = __builtin_amdgcn_mfma_f32_16x16x32_bf16(Al[mt], Bh, a, 0, 0, 0);
                acc[mt][nt] = a;
            }
    }

    // partial logits -> LDS  (D layout: n = lane&15, m = quad*4 + reg)
#pragma unroll
    for (int mt = 0; mt < 2; ++mt)
#pragma unroll
        for (int nt = 0; nt < 2; ++nt)
#pragma unroll
            for (int r = 0; r < 4; ++r)
                lg[kh][mt * 16 + q * 4 + r][nh * 32 + nt * 16 + c] = acc[mt][nt][r];
    __syncthreads();

    // ---- epilogue (verified rounds 1-3): lane = expert, 8 tokens/wave ----
    float usage_acc = 0.f;
#pragma unroll 1
    for (int j = 0; j < 8; ++j) {
        const int tl = wv * 8 + j;
        const int t  = t0 + tl;
        float l = lg[0][tl][lane] + lg[1][tl][lane];

        float v1 = l; int i1 = lane;
#pragma unroll
        for (int off = 32; off >= 1; off >>= 1) {
            float ov = __shfl_xor(v1, off, 64);
            int   oi = __shfl_xor(i1, off, 64);
            if (ov > v1 || (ov == v1 && oi < i1)) { v1 = ov; i1 = oi; }
        }
        float lm = (lane == i1) ? -INFINITY : l;
        float v2 = lm; int i2 = lane;
#pragma unroll
        for (int off = 32; off >= 1; off >>= 1) {
            float ov = __shfl_xor(v2, off, 64);
            int   oi = __shfl_xor(i2, off, 64);
            if (ov > v2 || (ov == v2 && oi < i2)) { v2 = ov; i2 = oi; }
        }

        float p = expf(l - v1);
        float s = p;
#pragma unroll
        for (int off = 32; off >= 1; off >>= 1) s += __shfl_xor(s, off, 64);

        float e2  = expf(v2 - v1);
        float rcp = 1.0f / (1.0f + e2);
        usage_acc += p / s;

        if (lane == 0) {
            out[(size_t)t * 2 + 0]         = (float)i1;
            out[(size_t)t * 2 + 1]         = (float)i2;
            out[32768 + (size_t)t * 2 + 0] = rcp;
            out[32768 + (size_t)t * 2 + 1] = e2 * rcp;
        }
    }

    // per-block usage partials (no atomics; deterministic)
    ured[wv][lane] = usage_acc;
    __syncthreads();
    if (wv == 0) {
        float s = ((ured[0][lane] + ured[1][lane]) + (ured[2][lane] + ured[3][lane]));
        usage_part[(size_t)blockIdx.x * 64 + lane] = s;
    }
}

__global__ void router_aux(const float* __restrict__ usage_part, float* __restrict__ out) {
    __shared__ float red[4][NE];
    const int tid  = threadIdx.x;   // 256
    const int e    = tid & 63;
    const int part = tid >> 6;      // 0..3
    float s = 0.f;
    for (int b = part; b < NBLK; b += 4) s += usage_part[(size_t)b * 64 + e];
    red[part][e] = s;
    __syncthreads();
    if (part == 0) {
        float u = ((red[0][e] + red[1][e]) + (red[2][e] + red[3][e]))
                  * (1.0f / 16384.0f) - (1.0f / 64.0f);
        float sq = u * u;
#pragma unroll
        for (int off = 32; off >= 1; off >>= 1) sq += __shfl_xor(sq, off, 64);
        if (e == 0) out[65536] = sq;
    }
}

extern "C" void kernel_launch(void* const* d_in, const int* in_sizes, int n_in,
                              void* d_out, int out_size, void* d_ws, size_t ws_size,
                              hipStream_t stream) {
    const float* x = (const float*)d_in[0];   // [4,4096,2048] fp32
    const float* W = (const float*)d_in[1];   // [64,2048] fp32
    float* out     = (float*)d_out;           // 65537 floats

    // ws layout: Wh | Wm | Wl (bf16 planes, 256 KB each) | usage partials (128 KB)
    unsigned short* ws_h = (unsigned short*)d_ws;
    unsigned short* ws_m = ws_h + NPLANE;
    unsigned short* ws_l = ws_m + NPLANE;
    float* upart         = (float*)(ws_l + NPLANE);

    wsplit_kernel<<<dim3(NPLANE / 256), dim3(256), 0, stream>>>(W, ws_h, ws_m, ws_l);
    router_main<<<dim3(NBLK), dim3(256), 0, stream>>>(x, ws_h, ws_m, ws_l, out, upart);
    router_aux<<<dim3(1), dim3(256), 0, stream>>>(upart, out);
}

// Round 5
// 273.995 us; speedup vs baseline: 1.5497x; 1.0289x over previous
//
#include <hip/hip_runtime.h>
#include <math.h>

// Problem constants (fixed by reference setup_inputs)
#define T_TOK 16384
#define DDIM  2048
#define NE    64
#define NPLANE (NE * DDIM)      // 131072 elements per W split plane
#define NBLK  512               // main-kernel grid (32 tokens each)

typedef __attribute__((ext_vector_type(8))) short short8;   // 8 bf16 MFMA frag
typedef __attribute__((ext_vector_type(4))) float floatx4;  // MFMA C/D

union Frag8 { unsigned short u[8]; short8 v; uint4 q; };

__device__ __forceinline__ unsigned int bf16_rne_bits(float x) {
    unsigned int u = __builtin_bit_cast(unsigned int, x);
    return (u + 0x7fffu + ((u >> 16) & 1u)) & 0xffff0000u;
}

// ---- pre-kernel: exact 3-way bf16 split of W (fp32 = h + m + l) ----
__global__ void wsplit_kernel(const float* __restrict__ W,
                              unsigned short* __restrict__ wh,
                              unsigned short* __restrict__ wm,
                              unsigned short* __restrict__ wl) {
    int i = blockIdx.x * 256 + threadIdx.x;   // grid covers exactly NPLANE
    float w = W[i];
    unsigned int hb = bf16_rne_bits(w);
    float r  = w - __builtin_bit_cast(float, hb);   // exact (Sterbenz)
    unsigned int mb = bf16_rne_bits(r);
    float r2 = r - __builtin_bit_cast(float, mb);   // exact
    unsigned int lb = bf16_rne_bits(r2);            // |err| <= 2^-24 |w|
    wh[i] = (unsigned short)(hb >> 16);
    wm[i] = (unsigned short)(mb >> 16);
    wl[i] = (unsigned short)(lb >> 16);
}

// ---- main: split-bf16 MFMA GEMM (6 passes = fp32-class accuracy) + top-2 ----
// Block: 512 threads = 8 waves = (expert-half nh) x (k-quarter kq).
// Wave tile: 32 tokens (2 m-tiles) x 32 experts (2 n-tiles) x 512 k.
// launch_bounds(512,4): 16 waves/CU (2 blocks co-resident), VGPR cap 128.
__global__ __launch_bounds__(512, 4)
void router_main(const float* __restrict__ x,
                 const unsigned short* __restrict__ wh,
                 const unsigned short* __restrict__ wm,
                 const unsigned short* __restrict__ wl,
                 float* __restrict__ out, float* __restrict__ usage_part) {
    __shared__ float lg[4][32][NE];    // per-k-quarter partial logits (32 KB)
    __shared__ float ured[8][NE];

    const int tid  = threadIdx.x;
    const int lane = tid & 63;
    const int wv   = __builtin_amdgcn_readfirstlane(tid >> 6);  // 0..7
    const int nh   = wv & 1;     // expert half (32 experts)
    const int kq   = wv >> 1;    // k quarter   (512 k)
    const int c    = lane & 15;  // frag row index (token / expert)
    const int q    = lane >> 4;  // frag k-quad
    const int t0   = blockIdx.x * 32;

    // A: token rows (fp32), B: expert rows in pre-split planes (L2-resident)
    const float* xr0 = x + (size_t)(t0 + c) * DDIM + kq * 512 + q * 8;
    const float* xr1 = xr0 + (size_t)16 * DDIM;
    const size_t bo0 = (size_t)(nh * 32 + c) * DDIM + kq * 512 + q * 8;
    const size_t bo1 = bo0 + (size_t)16 * DDIM;

    floatx4 acc[2][2];
#pragma unroll
    for (int mt = 0; mt < 2; ++mt)
#pragma unroll
        for (int nt = 0; nt < 2; ++nt)
            acc[mt][nt] = (floatx4){0.f, 0.f, 0.f, 0.f};

#pragma unroll 1
    for (int s = 0; s < 16; ++s) {
        const int sk = s * 32;
        // all loads clustered at iteration top (one latency exposure per step;
        // hidden by 4 waves/SIMD TLP)
        float4 ca[2][2];
        ca[0][0] = *(const float4*)(xr0 + sk);
        ca[0][1] = *(const float4*)(xr0 + sk + 4);
        ca[1][0] = *(const float4*)(xr1 + sk);
        ca[1][1] = *(const float4*)(xr1 + sk + 4);
        uint4 cb[2][3];
        cb[0][0] = *(const uint4*)(wh + bo0 + sk);
        cb[0][1] = *(const uint4*)(wm + bo0 + sk);
        cb[0][2] = *(const uint4*)(wl + bo0 + sk);
        cb[1][0] = *(const uint4*)(wh + bo1 + sk);
        cb[1][1] = *(const uint4*)(wm + bo1 + sk);
        cb[1][2] = *(const uint4*)(wl + bo1 + sk);

        // exact in-register 3-way split of A (proven numerics from round 4)
        short8 Ah[2], Am[2], Al[2];
#pragma unroll
        for (int mt = 0; mt < 2; ++mt) {
            Frag8 fh, fm, fl;
            float f[8] = {ca[mt][0].x, ca[mt][0].y, ca[mt][0].z, ca[mt][0].w,
                          ca[mt][1].x, ca[mt][1].y, ca[mt][1].z, ca[mt][1].w};
#pragma unroll
            for (int j = 0; j < 8; ++j) {
                unsigned int hb = bf16_rne_bits(f[j]);
                float r  = f[j] - __builtin_bit_cast(float, hb);
                unsigned int mb = bf16_rne_bits(r);
                float r2 = r - __builtin_bit_cast(float, mb);
                unsigned int lb = bf16_rne_bits(r2);
                fh.u[j] = (unsigned short)(hb >> 16);
                fm.u[j] = (unsigned short)(mb >> 16);
                fl.u[j] = (unsigned short)(lb >> 16);
            }
            Ah[mt] = fh.v; Am[mt] = fm.v; Al[mt] = fl.v;
        }

        // 6 passes: hh + hm + mh + mm + hl + lh
#pragma unroll
        for (int mt = 0; mt < 2; ++mt)
#pragma unroll
            for (int nt = 0; nt < 2; ++nt) {
                short8 Bh = __builtin_bit_cast(short8, cb[nt][0]);
                short8 Bm = __builtin_bit_cast(short8, cb[nt][1]);
                short8 Bl = __builtin_bit_cast(short8, cb[nt][2]);
                floatx4 a = acc[mt][nt];
                a = __builtin_amdgcn_mfma_f32_16x16x32_bf16(Ah[mt], Bh, a, 0, 0, 0);
                a = __builtin_amdgcn_mfma_f32_16x16x32_bf16(Ah[mt], Bm, a, 0, 0, 0);
                a = __builtin_amdgcn_mfma_f32_16x16x32_bf16(Am[mt], Bh, a, 0, 0, 0);
                a = __builtin_amdgcn_mfma_f32_16x16x32_bf16(Am[mt], Bm, a, 0, 0, 0);
                a = __builtin_amdgcn_mfma_f32_16x16x32_bf16(Ah[mt], Bl, a, 0, 0, 0);
                a = __builtin_amdgcn_mfma_f32_16x16x32_bf16(Al[mt], Bh, a, 0, 0, 0);
                acc[mt][nt] = a;
            }
    }

    // partial logits -> LDS  (D layout: n = lane&15, m = quad*4 + reg)
#pragma unroll
    for (int mt = 0; mt < 2; ++mt)
#pragma unroll
        for (int nt = 0; nt < 2; ++nt)
#pragma unroll
            for (int r = 0; r < 4; ++r)
                lg[kq][mt * 16 + q * 4 + r][nh * 32 + nt * 16 + c] = acc[mt][nt][r];
    __syncthreads();

    // ---- epilogue (verified rounds 1-4): lane = expert, 4 tokens/wave ----
    float usage_acc = 0.f;
#pragma unroll 1
    for (int j = 0; j < 4; ++j) {
        const int tl = wv * 4 + j;
        const int t  = t0 + tl;
        float l = (lg[0][tl][lane] + lg[1][tl][lane]) +
                  (lg[2][tl][lane] + lg[3][tl][lane]);

        float v1 = l; int i1 = lane;
#pragma unroll
        for (int off = 32; off >= 1; off >>= 1) {
            float ov = __shfl_xor(v1, off, 64);
            int   oi = __shfl_xor(i1, off, 64);
            if (ov > v1 || (ov == v1 && oi < i1)) { v1 = ov; i1 = oi; }
        }
        float lm = (lane == i1) ? -INFINITY : l;
        float v2 = lm; int i2 = lane;
#pragma unroll
        for (int off = 32; off >= 1; off >>= 1) {
            float ov = __shfl_xor(v2, off, 64);
            int   oi = __shfl_xor(i2, off, 64);
            if (ov > v2 || (ov == v2 && oi < i2)) { v2 = ov; i2 = oi; }
        }

        float p = expf(l - v1);
        float s = p;
#pragma unroll
        for (int off = 32; off >= 1; off >>= 1) s += __shfl_xor(s, off, 64);

        float e2  = expf(v2 - v1);
        float rcp = 1.0f / (1.0f + e2);
        usage_acc += p / s;

        if (lane == 0) {
            out[(size_t)t * 2 + 0]         = (float)i1;
            out[(size_t)t * 2 + 1]         = (float)i2;
            out[32768 + (size_t)t * 2 + 0] = rcp;
            out[32768 + (size_t)t * 2 + 1] = e2 * rcp;
        }
    }

    // per-block usage partials (no atomics; deterministic)
    ured[wv][lane] = usage_acc;
    __syncthreads();
    if (wv == 0) {
        float s = ((ured[0][lane] + ured[1][lane]) + (ured[2][lane] + ured[3][lane])) +
                  ((ured[4][lane] + ured[5][lane]) + (ured[6][lane] + ured[7][lane]));
        usage_part[(size_t)blockIdx.x * 64 + lane] = s;
    }
}

__global__ void router_aux(const float* __restrict__ usage_part, float* __restrict__ out) {
    __shared__ float red[4][NE];
    const int tid  = threadIdx.x;   // 256
    const int e    = tid & 63;
    const int part = tid >> 6;      // 0..3
    float s = 0.f;
    for (int b = part; b < NBLK; b += 4) s += usage_part[(size_t)b * 64 + e];
    red[part][e] = s;
    __syncthreads();
    if (part == 0) {
        float u = ((red[0][e] + red[1][e]) + (red[2][e] + red[3][e]))
                  * (1.0f / 16384.0f) - (1.0f / 64.0f);
        float sq = u * u;
#pragma unroll
        for (int off = 32; off >= 1; off >>= 1) sq += __shfl_xor(sq, off, 64);
        if (e == 0) out[65536] = sq;
    }
}

extern "C" void kernel_launch(void* const* d_in, const int* in_sizes, int n_in,
                              void* d_out, int out_size, void* d_ws, size_t ws_size,
                              hipStream_t stream) {
    const float* x = (const float*)d_in[0];   // [4,4096,2048] fp32
    const float* W = (const float*)d_in[1];   // [64,2048] fp32
    float* out     = (float*)d_out;           // 65537 floats

    // ws layout: Wh | Wm | Wl (bf16 planes, 256 KB each) | usage partials (128 KB)
    unsigned short* ws_h = (unsigned short*)d_ws;
    unsigned short* ws_m = ws_h + NPLANE;
    unsigned short* ws_l = ws_m + NPLANE;
    float* upart         = (float*)(ws_l + NPLANE);

    wsplit_kernel<<<dim3(NPLANE / 256), dim3(256), 0, stream>>>(W, ws_h, ws_m, ws_l);
    router_main<<<dim3(NBLK), dim3(512), 0, stream>>>(x, ws_h, ws_m, ws_l, out, upart);
    router_aux<<<dim3(1), dim3(256), 0, stream>>>(upart, out);
}

// Round 6
// 264.495 us; speedup vs baseline: 1.6053x; 1.0359x over previous
//
#include <hip/hip_runtime.h>
#include <math.h>

// Problem constants (fixed by reference setup_inputs)
#define T_TOK 16384
#define DDIM  2048
#define NE    64
#define NPLANE (NE * DDIM)      // 131072 elements per W split plane
#define NBLK  512               // main-kernel grid (32 tokens each)

typedef __attribute__((ext_vector_type(8))) short short8;   // 8 bf16 MFMA frag
typedef __attribute__((ext_vector_type(4))) float floatx4;  // MFMA C/D

union Frag8 { unsigned short u[8]; short8 v; };

__device__ __forceinline__ unsigned int bf16_rne_bits(float x) {
    unsigned int u = __builtin_bit_cast(unsigned int, x);
    return (u + 0x7fffu + ((u >> 16) & 1u)) & 0xffff0000u;
}

// async global->LDS DMA, 16 B per lane; LDS dest = uniform base + lane*16
__device__ __forceinline__ void dma16(const float* g, float* lds) {
    __builtin_amdgcn_global_load_lds(
        (const __attribute__((address_space(1))) unsigned int*)g,
        (__attribute__((address_space(3))) unsigned int*)lds, 16, 0, 0);
}

// ---- pre-kernel: exact 3-way bf16 split of W (fp32 = h + m + l) ----
__global__ void wsplit_kernel(const float* __restrict__ W,
                              unsigned short* __restrict__ wh,
                              unsigned short* __restrict__ wm,
                              unsigned short* __restrict__ wl) {
    int i = blockIdx.x * 256 + threadIdx.x;   // grid covers exactly NPLANE
    float w = W[i];
    unsigned int hb = bf16_rne_bits(w);
    float r  = w - __builtin_bit_cast(float, hb);   // exact
    unsigned int mb = bf16_rne_bits(r);
    float r2 = r - __builtin_bit_cast(float, mb);   // exact
    unsigned int lb = bf16_rne_bits(r2);            // |err| <= 2^-24 |w|
    wh[i] = (unsigned short)(hb >> 16);
    wm[i] = (unsigned short)(mb >> 16);
    wl[i] = (unsigned short)(lb >> 16);
}

// ---- main: DMA-staged A, split-bf16 MFMA (6 passes), top-2 epilogue ----
// Block: 512 thr = 8 waves = (expert-half nh) x (k-quarter kq).
// Wave tile: 32 tokens x 32 experts x 512 k. A staged via global_load_lds.
__global__ __launch_bounds__(512, 4)
void router_main(const float* __restrict__ x,
                 const unsigned short* __restrict__ wh,
                 const unsigned short* __restrict__ wm,
                 const unsigned short* __restrict__ wl,
                 float* __restrict__ out, float* __restrict__ usage_part) {
    // A staging: 4 kq-slices x (8 k8-blocks x 32 tokens x 8 floats) = 32 KB
    __shared__ float As[4 * 2048];
    __shared__ float lg[4][32][NE];    // per-kq partial logits (32 KB)
    __shared__ float ured[8][NE];

    const int tid  = threadIdx.x;
    const int lane = tid & 63;
    const int wv   = __builtin_amdgcn_readfirstlane(tid >> 6);  // 0..7
    const int nh   = wv & 1;     // expert half (32 experts)
    const int kq   = wv >> 1;    // k quarter   (512 k)
    const int cl   = lane & 15;  // frag row index (token / expert)
    const int q    = lane >> 4;  // frag k-quad
    const int t0   = blockIdx.x * 32;

    // DMA lane role: 1 KB per issue = one k8-block (32 tokens x 32 B)
    const int dtok  = lane >> 1;
    const int dhalf = lane & 1;
    const float* xdma = x + (size_t)(t0 + dtok) * DDIM + kq * 512 + dhalf * 4;

    float* myslice = As + kq * 2048;

    floatx4 acc[2][2];
#pragma unroll
    for (int mt = 0; mt < 2; ++mt)
#pragma unroll
        for (int nt = 0; nt < 2; ++nt)
            acc[mt][nt] = (floatx4){0.f, 0.f, 0.f, 0.f};

    const size_t bbase = (size_t)(nh * 32 + cl) * DDIM + kq * 512 + q * 8;

#pragma unroll 1
    for (int c = 0; c < 8; ++c) {
        // issue this chunk's DMA (nh pair covers k8 0..7 of the kq slice)
#pragma unroll
        for (int j = 0; j < 4; ++j) {
            const int k8 = nh * 4 + j;
            dma16(xdma + c * 64 + k8 * 8, myslice + k8 * 256);
        }
        __syncthreads();   // s_waitcnt vmcnt(0) before barrier drains the DMA

#pragma unroll
        for (int t = 0; t < 2; ++t) {
            // B frags (L2-resident split planes)
            const size_t bo = bbase + c * 64 + t * 32;
            uint4 cb[2][3];
#pragma unroll
            for (int nt = 0; nt < 2; ++nt) {
                const size_t o = bo + (size_t)nt * 16 * DDIM;
                cb[nt][0] = *(const uint4*)(wh + o);
                cb[nt][1] = *(const uint4*)(wm + o);
                cb[nt][2] = *(const uint4*)(wl + o);
            }
            // A frags from LDS + truncation 3-way split (exact residuals)
            short8 Ah[2], Am[2], Al[2];
#pragma unroll
            for (int mt = 0; mt < 2; ++mt) {
                const float* ap = myslice + (t * 4 + q) * 256 + (mt * 16 + cl) * 8;
                float4 a0 = *(const float4*)(ap);
                float4 a1 = *(const float4*)(ap + 4);
                float f[8] = {a0.x, a0.y, a0.z, a0.w, a1.x, a1.y, a1.z, a1.w};
                Frag8 fh, fm, fl;
#pragma unroll
                for (int j = 0; j < 8; ++j) {
                    unsigned int ub = __builtin_bit_cast(unsigned int, f[j]);
                    unsigned int hb = ub & 0xffff0000u;
                    float r = f[j] - __builtin_bit_cast(float, hb);   // exact
                    unsigned int rb = __builtin_bit_cast(unsigned int, r);
                    unsigned int mb = rb & 0xffff0000u;
                    float r2 = r - __builtin_bit_cast(float, mb);     // exact
                    unsigned int lb = __builtin_bit_cast(unsigned int, r2);
                    fh.u[j] = (unsigned short)(hb >> 16);
                    fm.u[j] = (unsigned short)(mb >> 16);
                    fl.u[j] = (unsigned short)(lb >> 16);
                }
                Ah[mt] = fh.v; Am[mt] = fm.v; Al[mt] = fl.v;
            }

            // 6 passes: hh + hm + mh + mm + hl + lh
#pragma unroll
            for (int mt = 0; mt < 2; ++mt)
#pragma unroll
                for (int nt = 0; nt < 2; ++nt) {
                    short8 Bh = __builtin_bit_cast(short8, cb[nt][0]);
                    short8 Bm = __builtin_bit_cast(short8, cb[nt][1]);
                    short8 Bl = __builtin_bit_cast(short8, cb[nt][2]);
                    floatx4 a = acc[mt][nt];
                    a = __builtin_amdgcn_mfma_f32_16x16x32_bf16(Ah[mt], Bh, a, 0, 0, 0);
                    a = __builtin_amdgcn_mfma_f32_16x16x32_bf16(Ah[mt], Bm, a, 0, 0, 0);
                    a = __builtin_amdgcn_mfma_f32_16x16x32_bf16(Am[mt], Bh, a, 0, 0, 0);
                    a = __builtin_amdgcn_mfma_f32_16x16x32_bf16(Am[mt], Bm, a, 0, 0, 0);
                    a = __builtin_amdgcn_mfma_f32_16x16x32_bf16(Ah[mt], Bl, a, 0, 0, 0);
                    a = __builtin_amdgcn_mfma_f32_16x16x32_bf16(Al[mt], Bh, a, 0, 0, 0);
                    acc[mt][nt] = a;
                }
        }
        __syncthreads();   // protect As before next chunk's DMA overwrites
    }

    // partial logits -> LDS  (D layout: n = lane&15, m = quad*4 + reg)
#pragma unroll
    for (int mt = 0; mt < 2; ++mt)
#pragma unroll
        for (int nt = 0; nt < 2; ++nt)
#pragma unroll
            for (int r = 0; r < 4; ++r)
                lg[kq][mt * 16 + q * 4 + r][nh * 32 + nt * 16 + cl] = acc[mt][nt][r];
    __syncthreads();

    // ---- epilogue (verified rounds 1-5): lane = expert, 4 tokens/wave ----
    float usage_acc = 0.f;
#pragma unroll 1
    for (int j = 0; j < 4; ++j) {
        const int tl = wv * 4 + j;
        const int t  = t0 + tl;
        float l = (lg[0][tl][lane] + lg[1][tl][lane]) +
                  (lg[2][tl][lane] + lg[3][tl][lane]);

        float v1 = l; int i1 = lane;
#pragma unroll
        for (int off = 32; off >= 1; off >>= 1) {
            float ov = __shfl_xor(v1, off, 64);
            int   oi = __shfl_xor(i1, off, 64);
            if (ov > v1 || (ov == v1 && oi < i1)) { v1 = ov; i1 = oi; }
        }
        float lm = (lane == i1) ? -INFINITY : l;
        float v2 = lm; int i2 = lane;
#pragma unroll
        for (int off = 32; off >= 1; off >>= 1) {
            float ov = __shfl_xor(v2, off, 64);
            int   oi = __shfl_xor(i2, off, 64);
            if (ov > v2 || (ov == v2 && oi < i2)) { v2 = ov; i2 = oi; }
        }

        float p = expf(l - v1);
        float s = p;
#pragma unroll
        for (int off = 32; off >= 1; off >>= 1) s += __shfl_xor(s, off, 64);

        float e2  = expf(v2 - v1);
        float rcp = 1.0f / (1.0f + e2);
        usage_acc += p / s;

        if (lane == 0) {
            out[(size_t)t * 2 + 0]         = (float)i1;
            out[(size_t)t * 2 + 1]         = (float)i2;
            out[32768 + (size_t)t * 2 + 0] = rcp;
            out[32768 + (size_t)t * 2 + 1] = e2 * rcp;
        }
    }

    // per-block usage partials (no atomics; deterministic)
    ured[wv][lane] = usage_acc;
    __syncthreads();
    if (wv == 0) {
        float s = ((ured[0][lane] + ured[1][lane]) + (ured[2][lane] + ured[3][lane])) +
                  ((ured[4][lane] + ured[5][lane]) + (ured[6][lane] + ured[7][lane]));
        usage_part[(size_t)blockIdx.x * 64 + lane] = s;
    }
}

__global__ void router_aux(const float* __restrict__ usage_part, float* __restrict__ out) {
    __shared__ float red[4][NE];
    const int tid  = threadIdx.x;   // 256
    const int e    = tid & 63;
    const int part = tid >> 6;      // 0..3
    float s = 0.f;
    for (int b = part; b < NBLK; b += 4) s += usage_part[(size_t)b * 64 + e];
    red[part][e] = s;
    __syncthreads();
    if (part == 0) {
        float u = ((red[0][e] + red[1][e]) + (red[2][e] + red[3][e]))
                  * (1.0f / 16384.0f) - (1.0f / 64.0f);
        float sq = u * u;
#pragma unroll
        for (int off = 32; off >= 1; off >>= 1) sq += __shfl_xor(sq, off, 64);
        if (e == 0) out[65536] = sq;
    }
}

extern "C" void kernel_launch(void* const* d_in, const int* in_sizes, int n_in,
                              void* d_out, int out_size, void* d_ws, size_t ws_size,
                              hipStream_t stream) {
    const float* x = (const float*)d_in[0];   // [4,4096,2048] fp32
    const float* W = (const float*)d_in[1];   // [64,2048] fp32
    float* out     = (float*)d_out;           // 65537 floats

    // ws layout: Wh | Wm | Wl (bf16 planes, 256 KB each) | usage partials (128 KB)
    unsigned short* ws_h = (unsigned short*)d_ws;
    unsigned short* ws_m = ws_h + NPLANE;
    unsigned short* ws_l = ws_m + NPLANE;
    float* upart         = (float*)(ws_l + NPLANE);

    wsplit_kernel<<<dim3(NPLANE / 256), dim3(256), 0, stream>>>(W, ws_h, ws_m, ws_l);
    router_main<<<dim3(NBLK), dim3(512), 0, stream>>>(x, ws_h, ws_m, ws_l, out, upart);
    router_aux<<<dim3(1), dim3(256), 0, stream>>>(upart, out);
}

// Round 7
// 236.113 us; speedup vs baseline: 1.7983x; 1.1202x over previous
//
#include <hip/hip_runtime.h>
#include <math.h>

// Problem constants (fixed by reference setup_inputs)
#define T_TOK 16384
#define DDIM  2048
#define NE    64
#define NPLANE (NE * DDIM)      // 131072 elements per W split plane
#define NBLK  512               // main-kernel grid (32 tokens each)

typedef __attribute__((ext_vector_type(8))) short short8;   // 8 bf16 MFMA frag
typedef __attribute__((ext_vector_type(4))) float floatx4;  // MFMA C/D

union Frag8 { unsigned short u[8]; short8 v; };

__device__ __forceinline__ unsigned int bf16_rne_bits(float x) {
    unsigned int u = __builtin_bit_cast(unsigned int, x);
    return (u + 0x7fffu + ((u >> 16) & 1u)) & 0xffff0000u;
}

// async global->LDS DMA, 16 B per lane; LDS dest = uniform base + lane*16
__device__ __forceinline__ void dma16(const float* g, float* lds) {
    __builtin_amdgcn_global_load_lds(
        (const __attribute__((address_space(1))) unsigned int*)g,
        (__attribute__((address_space(3))) unsigned int*)lds, 16, 0, 0);
}

// ---- pre-kernel: exact 3-way bf16 split of W (fp32 = h + m + l) ----
__global__ void wsplit_kernel(const float* __restrict__ W,
                              unsigned short* __restrict__ wh,
                              unsigned short* __restrict__ wm,
                              unsigned short* __restrict__ wl) {
    int i = blockIdx.x * 256 + threadIdx.x;   // grid covers exactly NPLANE
    float w = W[i];
    unsigned int hb = bf16_rne_bits(w);
    float r  = w - __builtin_bit_cast(float, hb);   // exact
    unsigned int mb = bf16_rne_bits(r);
    float r2 = r - __builtin_bit_cast(float, mb);   // exact
    unsigned int lb = bf16_rne_bits(r2);            // |err| <= 2^-24 |w|
    wh[i] = (unsigned short)(hb >> 16);
    wm[i] = (unsigned short)(mb >> 16);
    wl[i] = (unsigned short)(lb >> 16);
}

// ---- main: double-buffered DMA A-staging, split-bf16 MFMA, top-2 ----
// Block: 512 thr = 8 waves = (expert-half nh) x (k-quarter kq).
// Wave tile: 32 tokens x 32 experts x 512 k.
// LDS: As[2][8192] double buffer (64 KB); lg (32 KB) OVERLAYS As[0]
// (only live after the K-loop); ured separate 2 KB. Total 66 KB -> 2 blk/CU.
__global__ __launch_bounds__(512, 4)
void router_main(const float* __restrict__ x,
                 const unsigned short* __restrict__ wh,
                 const unsigned short* __restrict__ wm,
                 const unsigned short* __restrict__ wl,
                 float* __restrict__ out, float* __restrict__ usage_part) {
    __shared__ float As[2 * 8192];     // 64 KB
    __shared__ float ured[8][NE];      // 2 KB
    float* lg = As;                    // [4][32][64] overlay on buffer 0

    const int tid  = threadIdx.x;
    const int lane = tid & 63;
    const int wv   = __builtin_amdgcn_readfirstlane(tid >> 6);  // 0..7
    const int nh   = wv & 1;     // expert half (32 experts)
    const int kq   = wv >> 1;    // k quarter   (512 k)
    const int cl   = lane & 15;  // frag row index (token / expert)
    const int q    = lane >> 4;  // frag k-quad
    const int t0   = blockIdx.x * 32;

    // DMA lane role (token-major: conflict-free consumer reads):
    // lane l stages token (l&31), float4-half (l>>5)
    const float* xdma = x + (size_t)(t0 + (lane & 31)) * DDIM + kq * 512 + (lane >> 5) * 4;

    floatx4 acc[2][2];
#pragma unroll
    for (int mt = 0; mt < 2; ++mt)
#pragma unroll
        for (int nt = 0; nt < 2; ++nt)
            acc[mt][nt] = (floatx4){0.f, 0.f, 0.f, 0.f};

    const size_t bbase = (size_t)(nh * 32 + cl) * DDIM + kq * 512 + q * 8;

    // prologue: DMA chunk 0 -> buffer 0
#pragma unroll
    for (int j = 0; j < 4; ++j) {
        const int k8 = nh * 4 + j;
        dma16(xdma + k8 * 8, As + kq * 2048 + k8 * 256);
    }

#pragma unroll 1
    for (int c = 0; c < 8; ++c) {
        __syncthreads();   // drains DMA(c); also frees buf[(c+1)&1] for prefetch

        if (c + 1 < 8) {   // prefetch next chunk into alternate buffer
            float* nb = As + ((c + 1) & 1) * 8192 + kq * 2048;
#pragma unroll
            for (int j = 0; j < 4; ++j) {
                const int k8 = nh * 4 + j;
                dma16(xdma + (c + 1) * 64 + k8 * 8, nb + k8 * 256);
            }
        }

        const float* buf = As + (c & 1) * 8192 + kq * 2048;

#pragma unroll
        for (int t = 0; t < 2; ++t) {
            // B frags (L2-resident split planes)
            const size_t bo = bbase + c * 64 + t * 32;
            uint4 cb[2][3];
#pragma unroll
            for (int nt = 0; nt < 2; ++nt) {
                const size_t o = bo + (size_t)nt * 16 * DDIM;
                cb[nt][0] = *(const uint4*)(wh + o);
                cb[nt][1] = *(const uint4*)(wm + o);
                cb[nt][2] = *(const uint4*)(wl + o);
            }
            // A frags from LDS + truncation 3-way split (exact residuals)
            short8 Ah[2], Am[2], Al[2];
#pragma unroll
            for (int mt = 0; mt < 2; ++mt) {
                const float* ap = buf + (t * 4 + q) * 256 + (mt * 16 + cl) * 4;
                float4 a0 = *(const float4*)(ap);        // k j=0..3
                float4 a1 = *(const float4*)(ap + 128);  // k j=4..7
                float f[8] = {a0.x, a0.y, a0.z, a0.w, a1.x, a1.y, a1.z, a1.w};
                Frag8 fh, fm, fl;
#pragma unroll
                for (int j = 0; j < 8; ++j) {
                    unsigned int ub = __builtin_bit_cast(unsigned int, f[j]);
                    unsigned int hb = ub & 0xffff0000u;
                    float r = f[j] - __builtin_bit_cast(float, hb);   // exact
                    unsigned int rb = __builtin_bit_cast(unsigned int, r);
                    unsigned int mb = rb & 0xffff0000u;
                    float r2 = r - __builtin_bit_cast(float, mb);     // exact
                    unsigned int lb = __builtin_bit_cast(unsigned int, r2);
                    fh.u[j] = (unsigned short)(hb >> 16);
                    fm.u[j] = (unsigned short)(mb >> 16);
                    fl.u[j] = (unsigned short)(lb >> 16);
                }
                Ah[mt] = fh.v; Am[mt] = fm.v; Al[mt] = fl.v;
            }

            // 6 passes: hh + hm + mh + mm + hl + lh
#pragma unroll
            for (int mt = 0; mt < 2; ++mt)
#pragma unroll
                for (int nt = 0; nt < 2; ++nt) {
                    short8 Bh = __builtin_bit_cast(short8, cb[nt][0]);
                    short8 Bm = __builtin_bit_cast(short8, cb[nt][1]);
                    short8 Bl = __builtin_bit_cast(short8, cb[nt][2]);
                    floatx4 a = acc[mt][nt];
                    a = __builtin_amdgcn_mfma_f32_16x16x32_bf16(Ah[mt], Bh, a, 0, 0, 0);
                    a = __builtin_amdgcn_mfma_f32_16x16x32_bf16(Ah[mt], Bm, a, 0, 0, 0);
                    a = __builtin_amdgcn_mfma_f32_16x16x32_bf16(Am[mt], Bh, a, 0, 0, 0);
                    a = __builtin_amdgcn_mfma_f32_16x16x32_bf16(Am[mt], Bm, a, 0, 0, 0);
                    a = __builtin_amdgcn_mfma_f32_16x16x32_bf16(Ah[mt], Bl, a, 0, 0, 0);
                    a = __builtin_amdgcn_mfma_f32_16x16x32_bf16(Al[mt], Bh, a, 0, 0, 0);
                    acc[mt][nt] = a;
                }
        }
    }

    // all waves past top-of-c=7 barrier: no one reads buffer 0 anymore ->
    // safe to overlay lg there. (c=7 compute reads buffer 1, disjoint.)
    // D layout: n(expert) = lane&15, m(token) = quad*4 + reg
#pragma unroll
    for (int mt = 0; mt < 2; ++mt)
#pragma unroll
        for (int nt = 0; nt < 2; ++nt)
#pragma unroll
            for (int r = 0; r < 4; ++r)
                lg[kq * 2048 + (mt * 16 + q * 4 + r) * 64 + nh * 32 + nt * 16 + cl]
                    = acc[mt][nt][r];
    __syncthreads();

    // ---- epilogue (verified rounds 1-6): lane = expert, 4 tokens/wave ----
    float usage_acc = 0.f;
#pragma unroll 1
    for (int j = 0; j < 4; ++j) {
        const int tl = wv * 4 + j;
        const int t  = t0 + tl;
        float l = (lg[0 * 2048 + tl * 64 + lane] + lg[1 * 2048 + tl * 64 + lane]) +
                  (lg[2 * 2048 + tl * 64 + lane] + lg[3 * 2048 + tl * 64 + lane]);

        float v1 = l; int i1 = lane;
#pragma unroll
        for (int off = 32; off >= 1; off >>= 1) {
            float ov = __shfl_xor(v1, off, 64);
            int   oi = __shfl_xor(i1, off, 64);
            if (ov > v1 || (ov == v1 && oi < i1)) { v1 = ov; i1 = oi; }
        }
        float lm = (lane == i1) ? -INFINITY : l;
        float v2 = lm; int i2 = lane;
#pragma unroll
        for (int off = 32; off >= 1; off >>= 1) {
            float ov = __shfl_xor(v2, off, 64);
            int   oi = __shfl_xor(i2, off, 64);
            if (ov > v2 || (ov == v2 && oi < i2)) { v2 = ov; i2 = oi; }
        }

        float p = expf(l - v1);
        float s = p;
#pragma unroll
        for (int off = 32; off >= 1; off >>= 1) s += __shfl_xor(s, off, 64);

        float e2  = expf(v2 - v1);
        float rcp = 1.0f / (1.0f + e2);
        usage_acc += p / s;

        if (lane == 0) {
            out[(size_t)t * 2 + 0]         = (float)i1;
            out[(size_t)t * 2 + 1]         = (float)i2;
            out[32768 + (size_t)t * 2 + 0] = rcp;
            out[32768 + (size_t)t * 2 + 1] = e2 * rcp;
        }
    }

    // per-block usage partials (no atomics; deterministic)
    ured[wv][lane] = usage_acc;
    __syncthreads();
    if (wv == 0) {
        float s = ((ured[0][lane] + ured[1][lane]) + (ured[2][lane] + ured[3][lane])) +
                  ((ured[4][lane] + ured[5][lane]) + (ured[6][lane] + ured[7][lane]));
        usage_part[(size_t)blockIdx.x * 64 + lane] = s;
    }
}

__global__ __launch_bounds__(1024)
void router_aux(const float* __restrict__ usage_part, float* __restrict__ out) {
    __shared__ float red[16][NE];
    const int tid = threadIdx.x;    // 1024
    const int e   = tid & 63;
    const int g   = tid >> 6;       // 0..15
    float s = 0.f;
#pragma unroll
    for (int i = 0; i < NBLK / 16; ++i)
        s += usage_part[(size_t)(g * (NBLK / 16) + i) * 64 + e];
    red[g][e] = s;
    __syncthreads();
    if (g == 0) {
        float tot = 0.f;
#pragma unroll
        for (int i = 0; i < 16; ++i) tot += red[i][e];
        float u = tot * (1.0f / 16384.0f) - (1.0f / 64.0f);
        float sq = u * u;
#pragma unroll
        for (int off = 32; off >= 1; off >>= 1) sq += __shfl_xor(sq, off, 64);
        if (e == 0) out[65536] = sq;
    }
}

extern "C" void kernel_launch(void* const* d_in, const int* in_sizes, int n_in,
                              void* d_out, int out_size, void* d_ws, size_t ws_size,
                              hipStream_t stream) {
    const float* x = (const float*)d_in[0];   // [4,4096,2048] fp32
    const float* W = (const float*)d_in[1];   // [64,2048] fp32
    float* out     = (float*)d_out;           // 65537 floats

    // ws layout: Wh | Wm | Wl (bf16 planes, 256 KB each) | usage partials (128 KB)
    unsigned short* ws_h = (unsigned short*)d_ws;
    unsigned short* ws_m = ws_h + NPLANE;
    unsigned short* ws_l = ws_m + NPLANE;
    float* upart         = (float*)(ws_l + NPLANE);

    wsplit_kernel<<<dim3(NPLANE / 256), dim3(256), 0, stream>>>(W, ws_h, ws_m, ws_l);
    router_main<<<dim3(NBLK), dim3(512), 0, stream>>>(x, ws_h, ws_m, ws_l, out, upart);
    router_aux<<<dim3(1), dim3(1024), 0, stream>>>(upart, out);
}